// Round 12
// baseline (1016.626 us; speedup 1.0000x reference)
//
#include <hip/hip_runtime.h>
#include <math.h>

#define BATCH  16384
#define TSTEPS 19
#define INW    17
#define HID    128
#define NROW   16          // batch rows per WG -> grid = 1024 = 4 blocks/CU
#define THREADS 256        // 4 waves; wave wv owns n_tiles {wv, 4+wv, ..., 28+wv}
#define KP     136         // padded row length (halfs) for h state (128+8)
#define KP0    40          // padded row length (halfs) for x (32+8)

typedef _Float16 f16x8 __attribute__((ext_vector_type(8)));
typedef float    f32x4 __attribute__((ext_vector_type(4)));

// ---- ws layout (halfs), MFMA-fragment-ordered tiles ----
#define W_BIG      0                 // 5 * 131072 = 655360
#define W_IH0      655360            // [512][32]: n_tile 0..31, tiles of 1024 (hi512|lo512)
#define W_HEAD     688128            // [32 rows][128]: (n_tile 0..1, ks 0..3) tiles of 1024
#define WS_HALFS   696320

__device__ __forceinline__ float fast_rcp(float x) { return __builtin_amdgcn_rcpf(x); }
__device__ __forceinline__ float sigm(float z)  { return fast_rcp(1.0f + __expf(-z)); }
__device__ __forceinline__ float tanh_(float z) { return 1.0f - 2.0f * fast_rcp(1.0f + __expf(2.0f * z)); }

// ---------------- weight conversion: fp32 -> f16 hi (lo planes written but unused) ----------------
__global__ void convert_w(const float* __restrict__ Whh0, const float* __restrict__ Whh1,
                          const float* __restrict__ Whh2, const float* __restrict__ Wih1,
                          const float* __restrict__ Wih2, const float* __restrict__ Wih0,
                          const float* __restrict__ Wl, _Float16* __restrict__ ws)
{
    int idx = blockIdx.x * 256 + threadIdx.x;
    if (idx < 327680) {
        int m = idx >> 16, e = idx & 65535;
        int r = e >> 7, k = e & 127;
        const float* src = (m == 0) ? Whh0 : (m == 1) ? Whh1 : (m == 2) ? Whh2
                          : (m == 3) ? Wih1 : Wih2;
        float v = src[e];
        _Float16 hi = (_Float16)v;
        int n_tile = r >> 4, colr = r & 15, ks = k >> 5, qd = (k >> 3) & 3, j = k & 7;
        int dst = W_BIG + m * 131072 + (n_tile * 4 + ks) * 1024 + (qd * 16 + colr) * 8 + j;
        ws[dst]       = hi;
        ws[dst + 512] = (_Float16)(v - (float)hi);
    } else if (idx < 344064) {
        int e = idx - 327680;              // [0, 16384)
        int r = e >> 5, k = e & 31;
        float v = (k < INW) ? Wih0[r * INW + k] : 0.0f;
        _Float16 hi = (_Float16)v;
        int n_tile = r >> 4, colr = r & 15, qd = k >> 3, j = k & 7;
        int dst = W_IH0 + n_tile * 1024 + (qd * 16 + colr) * 8 + j;
        ws[dst]       = hi;
        ws[dst + 512] = (_Float16)(v - (float)hi);
    } else if (idx < 348160) {
        int e = idx - 344064;              // [0, 4096)
        int r = e >> 7, k = e & 127;
        float v = (r < INW) ? Wl[(size_t)r * HID + k] : 0.0f;
        _Float16 hi = (_Float16)v;
        int n_tile = r >> 4, colr = r & 15, ks = k >> 5, qd = (k >> 3) & 3, j = k & 7;
        int dst = W_HEAD + (n_tile * 4 + ks) * 1024 + (qd * 16 + colr) * 8 + j;
        ws[dst]       = hi;
        ws[dst + 512] = (_Float16)(v - (float)hi);
    }
}

// ---------------- GEMM helpers (software-pipelined, sched_barrier-fenced) ----------------
// acc[j]: rows m = quad*4 + r, cols n = (j*4 + wv)*16 + col   (j = 0..7)
// Pure-f16 gemm (round 10/11: both lo corrections dropped, absmax bit-neutral).
// A from LDS h plane (row-major stride KP); B fragment tiles (coalesced lane*8).
// Pipeline: B tiles 8-slot (issued 8 regions ahead ~= L2 latency); A frags dbuf per ks.
__device__ __forceinline__ void gemm_h(f32x4 acc[8],
                                       const _Float16* __restrict__ A,
                                       const _Float16* __restrict__ B,
                                       int col, int q8, int wv, int lane)
{
    const _Float16* a_p = A + col * KP;
    const int l8 = lane * 8;
    const _Float16* Bw = B + (wv * 4) * 1024 + l8;   // tile (j,ks) at Bw + (j*16+ks)*1024

    f16x8 bh[8];
    f16x8 ah[2];

    // prologue: A frag for ks=0; B tiles for regions 0..7 (j=0..7 of ks=0)
    ah[0] = *(const f16x8*)(a_p + q8);
#pragma unroll
    for (int p = 0; p < 8; ++p)
        bh[p] = *(const f16x8*)(Bw + (p * 16) * 1024);
    __builtin_amdgcn_sched_barrier(0);

#pragma unroll
    for (int it = 0; it < 32; ++it) {
        const int ks = it >> 3, j = it & 7;
        const int sl = it & 7;      // B slot (8-deep)
        const int ka = ks & 1;      // A slot
        __builtin_amdgcn_s_setprio(1);
        acc[j] = __builtin_amdgcn_mfma_f32_16x16x32_f16(ah[ka], bh[sl], acc[j], 0, 0, 0);
        __builtin_amdgcn_s_setprio(0);
        // issue B load for region it+8 (same j, ks+1) into the just-freed slot
        if (it < 24)
            bh[sl] = *(const f16x8*)(Bw + (j * 16 + (ks + 1)) * 1024);
        // issue A frag load for ks+1 early in each ks (consumed 8 regions later)
        if (j == 0 && ks < 3)
            ah[ka ^ 1] = *(const f16x8*)(a_p + (ks + 1) * 32 + q8);
        __builtin_amdgcn_sched_barrier(0);   // pin the pipeline: nothing crosses
    }
}

// x-part for layer 0: K=32 (padded), 8 regions, 4-slot B pipeline (1/21 of work)
__device__ __forceinline__ void gemm_x(f32x4 acc[8],
                                       const _Float16* __restrict__ X,
                                       const _Float16* __restrict__ B,
                                       int col, int q8, int wv, int lane)
{
    const int l8 = lane * 8;
    const _Float16* Bw = B + wv * 1024 + l8;         // tile j at Bw + j*4*1024
    f16x8 ah = *(const f16x8*)(X + col * KP0 + q8);
    f16x8 bh[4];
#pragma unroll
    for (int p = 0; p < 4; ++p)
        bh[p] = *(const f16x8*)(Bw + p * 4 * 1024);
    __builtin_amdgcn_sched_barrier(0);
#pragma unroll
    for (int j = 0; j < 8; ++j) {
        const int sl = j & 3;
        __builtin_amdgcn_s_setprio(1);
        acc[j] = __builtin_amdgcn_mfma_f32_16x16x32_f16(ah, bh[sl], acc[j], 0, 0, 0);
        __builtin_amdgcn_s_setprio(0);
        if (j < 4)
            bh[sl] = *(const f16x8*)(Bw + (j + 4) * 4 * 1024);
        __builtin_amdgcn_sched_barrier(0);
    }
}

// gates + h write for one layer.
// Lane holds, for col groups cg=0,1 (c = cg*64 + wv*16 + col) and rows r=0..3:
//   zi = acc[0+cg][r], zf = acc[2+cg][r], zg = acc[4+cg][r], zo = acc[6+cg][r]
__device__ __forceinline__ void gates_store(f32x4 acc[8], f32x4 cst[2],
                                            _Float16* __restrict__ HsP,
                                            int quad, int col, int wv)
{
#pragma unroll
    for (int cg = 0; cg < 2; ++cg) {
        const int c = cg * 64 + wv * 16 + col;
#pragma unroll
        for (int r = 0; r < 4; ++r) {
            float zi = acc[0 + cg][r];
            float zf = acc[2 + cg][r];
            float zg = acc[4 + cg][r];
            float zo = acc[6 + cg][r];
            float ig = sigm(zi), fg = sigm(zf), og = sigm(zo), gg = tanh_(zg);
            float cn = fg * cst[cg][r] + ig * gg;
            cst[cg][r] = cn;
            float h = og * tanh_(cn);
            int m = quad * 4 + r;
            HsP[m * KP + c] = (_Float16)h;
        }
    }
}

// out[:, t, :] = h2 @ Wl^T + bl (waves 0..1 only: nt = wv)
__device__ __forceinline__ void head_out(const _Float16* __restrict__ wsp,
                                         const _Float16* __restrict__ Hs2,
                                         float* __restrict__ out, int b0, int t,
                                         int wv, int lane, int col, int quad, int q8,
                                         float blv)
{
    const int nt = wv;
    const _Float16* ah = Hs2 + col * KP;
    f32x4 o = (f32x4){0, 0, 0, 0};
#pragma unroll
    for (int ks = 0; ks < 4; ++ks) {
        const _Float16* bt = wsp + W_HEAD + (nt * 4 + ks) * 1024 + lane * 8;
        f16x8 a_h = *(const f16x8*)(ah + ks * 32 + q8);
        f16x8 b_h = *(const f16x8*)(bt);
        o = __builtin_amdgcn_mfma_f32_16x16x32_f16(a_h, b_h, o, 0, 0, 0);
    }
    int i = nt * 16 + col;
    if (i < INW) {
#pragma unroll
        for (int r = 0; r < 4; ++r) {
            int m = quad * 4 + r;
            out[(size_t)(b0 + m) * (TSTEPS * INW) + t * INW + i] = o[r] + blv;
        }
    }
}

// ---------------- main kernel ----------------
// 3-barrier schedule (round 8), re-tiled to 16-row blocks for 4 blocks/CU:
//   rec-gemm Whh(l)*h_old(l)  [+ gemm_x / x-loads at l==0; Xs write at l==1; head(t-1) at l==2]
//   BARRIER   (anti-dep: all reads of Hs[l]-old done; visibility: h_new(l-1) published)
//   in-gemm Wih(l)*h_new(l-1)  [l>0]
//   gates(l) -> write Hs[l]
__global__ __launch_bounds__(THREADS, 4) void lstm_mfma(
    const float* __restrict__ x,
    const float* __restrict__ bih0, const float* __restrict__ bhh0,
    const float* __restrict__ bih1, const float* __restrict__ bhh1,
    const float* __restrict__ bih2, const float* __restrict__ bhh2,
    const float* __restrict__ bl,
    const _Float16* __restrict__ wsp,
    float* __restrict__ out)
{
    __shared__ _Float16 Hs[3][NROW][KP];      // [layer][m][k]  = 13056 B
    __shared__ _Float16 Xs[2][NROW][KP0];     // [buf][m][k]    = 2560 B
    __shared__ float    Bs[3][512];           // bih+bhh/layer  = 6144 B

    const int tid  = threadIdx.x;
    const int wv   = tid >> 6;
    const int lane = tid & 63;
    const int col  = lane & 15;
    const int quad = lane >> 4;
    const int q8   = quad * 8;
    const int b0   = blockIdx.x * NROW;

    // stage bias sums into LDS (saves persistent registers)
    for (int i = tid; i < 1536; i += THREADS) {
        int l = i >> 9, n = i & 511;
        const float* bi = (l == 0) ? bih0 : (l == 1) ? bih1 : bih2;
        const float* bh = (l == 0) ? bhh0 : (l == 1) ? bhh1 : bhh2;
        Bs[l][n] = bi[n] + bh[n];
    }
    // zero h state: 13056 B = 3264 floats
    for (int i = tid; i < 3264; i += THREADS) ((float*)Hs)[i] = 0.0f;

    // stage x[:, 0, :] as f16 into buffer 0 (K padded to 32)
    for (int ii = tid; ii < NROW * 32; ii += THREADS) {
        int m = ii >> 5, k = ii & 31;
        float v = (k < INW) ? x[(size_t)(b0 + m) * (TSTEPS * INW) + k] : 0.0f;
        Xs[0][m][k] = (_Float16)v;
    }

    f32x4 cst[3][2];
#pragma unroll
    for (int l = 0; l < 3; ++l) { cst[l][0] = (f32x4){0,0,0,0}; cst[l][1] = (f32x4){0,0,0,0}; }

    // weight pointers (fragment-ordered)
    const _Float16* Whh[3] = {wsp + W_BIG,  wsp + W_BIG + 131072, wsp + W_BIG + 262144};
    const _Float16* Wih[3] = {wsp + W_IH0, wsp + W_BIG + 393216, wsp + W_BIG + 524288};

    // head bias (waves 0..1 only)
    float blv = 0.0f;
    {
        int i = wv * 16 + col;
        if (wv < 2 && i < INW) blv = bl[i];
    }

    __syncthreads();

    int tb = 0;
#pragma unroll 1
    for (int t = 0; t < TSTEPS; ++t) {
        const int nb = tb ^ 1;
        const int t2 = t + 1;
        float xva[2];

#pragma unroll 1
        for (int l = 0; l < 3; ++l) {
            f32x4 acc[8];
#pragma unroll
            for (int j = 0; j < 8; ++j) {
                float bv = Bs[l][(j * 4 + wv) * 16 + col];
                acc[j] = (f32x4){bv, bv, bv, bv};
            }

            if (l == 0) {
                // issue x[t+1] loads early (latency hides under the L0 gemms)
                if (t2 < TSTEPS) {
#pragma unroll
                    for (int u = 0; u < 2; ++u) {
                        int ii = tid + u * THREADS;
                        int m = ii >> 5, k = ii & 31;
                        xva[u] = (k < INW) ? x[(size_t)(b0 + m) * (TSTEPS * INW) + t2 * INW + k] : 0.0f;
                    }
                }
                gemm_x(acc, &Xs[tb][0][0], Wih[0], col, q8, wv, lane);
            }

            // recurrent contribution (reads Hs[l] OLD)
            gemm_h(acc, &Hs[l][0][0], Whh[l], col, q8, wv, lane);

            if (l == 1 && t2 < TSTEPS) {
                // write x[t+1] to the LDS double-buffer (loads landed during L0/L1 gemms)
#pragma unroll
                for (int u = 0; u < 2; ++u) {
                    int ii = tid + u * THREADS;
                    int m = ii >> 5, k = ii & 31;
                    Xs[nb][m][k] = (_Float16)xva[u];
                }
            }
            if (l == 2 && t > 0 && wv < 2)
                head_out(wsp, &Hs[2][0][0], out, b0, t - 1,
                         wv, lane, col, quad, q8, blv);

            __syncthreads();   // reads of Hs[l]-old done (all waves); h_new(l-1) visible

            // input contribution (reads Hs[l-1] NEW)
            if (l > 0)
                gemm_h(acc, &Hs[l - 1][0][0], Wih[l], col, q8, wv, lane);

            gates_store(acc, cst[l], &Hs[l][0][0], quad, col, wv);
            // no barrier here: next iteration's rec gemm touches a different Hs buffer
        }

        tb = nb;
    }

    __syncthreads();   // h2(T-1) visible for the epilogue head
    if (wv < 2)
        head_out(wsp, &Hs[2][0][0], out, b0, TSTEPS - 1,
                 wv, lane, col, quad, q8, blv);
}

extern "C" void kernel_launch(void* const* d_in, const int* in_sizes, int n_in,
                              void* d_out, int out_size, void* d_ws, size_t ws_size,
                              hipStream_t stream) {
    const float* x    = (const float*)d_in[0];
    const float* Wih0 = (const float*)d_in[1];
    const float* Whh0 = (const float*)d_in[2];
    const float* bih0 = (const float*)d_in[3];
    const float* bhh0 = (const float*)d_in[4];
    const float* Wih1 = (const float*)d_in[5];
    const float* Whh1 = (const float*)d_in[6];
    const float* bih1 = (const float*)d_in[7];
    const float* bhh1 = (const float*)d_in[8];
    const float* Wih2 = (const float*)d_in[9];
    const float* Whh2 = (const float*)d_in[10];
    const float* bih2 = (const float*)d_in[11];
    const float* bhh2 = (const float*)d_in[12];
    const float* Wl   = (const float*)d_in[13];
    const float* bl   = (const float*)d_in[14];
    float* out = (float*)d_out;
    _Float16* ws = (_Float16*)d_ws;

    convert_w<<<(348160 + 255) / 256, 256, 0, stream>>>(Whh0, Whh1, Whh2, Wih1, Wih2, Wih0, Wl, ws);
    lstm_mfma<<<BATCH / NROW, THREADS, 0, stream>>>(
        x, bih0, bhh0, bih1, bhh1, bih2, bhh2, bl, ws, out);
}

// Round 13
// 590.984 us; speedup vs baseline: 1.7202x; 1.7202x over previous
//
#include <hip/hip_runtime.h>
#include <math.h>

#define BATCH  16384
#define TSTEPS 19
#define INW    17
#define HID    128
#define NROW   16          // batch rows per WG -> grid = 1024 = 4 blocks/CU
#define THREADS 256        // 4 waves; wave wv owns n_tiles {wv, 4+wv, ..., 28+wv}
#define KP     136         // padded row length (halfs) for h state (128+8)
#define KP0    40          // padded row length (halfs) for x (32+8)

typedef _Float16 f16x8 __attribute__((ext_vector_type(8)));
typedef float    f32x4 __attribute__((ext_vector_type(4)));

// ---- ws layout (halfs), MFMA-fragment-ordered tiles ----
#define W_BIG      0                 // 5 * 131072 = 655360
#define W_IH0      655360            // [512][32]: n_tile 0..31, tiles of 1024 (hi512|lo512)
#define W_HEAD     688128            // [32 rows][128]: (n_tile 0..1, ks 0..3) tiles of 1024
#define WS_HALFS   696320

__device__ __forceinline__ float fast_rcp(float x) { return __builtin_amdgcn_rcpf(x); }
__device__ __forceinline__ float sigm(float z)  { return fast_rcp(1.0f + __expf(-z)); }
__device__ __forceinline__ float tanh_(float z) { return 1.0f - 2.0f * fast_rcp(1.0f + __expf(2.0f * z)); }

// ---------------- weight conversion: fp32 -> f16 hi (lo planes written but unused) ----------------
__global__ void convert_w(const float* __restrict__ Whh0, const float* __restrict__ Whh1,
                          const float* __restrict__ Whh2, const float* __restrict__ Wih1,
                          const float* __restrict__ Wih2, const float* __restrict__ Wih0,
                          const float* __restrict__ Wl, _Float16* __restrict__ ws)
{
    int idx = blockIdx.x * 256 + threadIdx.x;
    if (idx < 327680) {
        int m = idx >> 16, e = idx & 65535;
        int r = e >> 7, k = e & 127;
        const float* src = (m == 0) ? Whh0 : (m == 1) ? Whh1 : (m == 2) ? Whh2
                          : (m == 3) ? Wih1 : Wih2;
        float v = src[e];
        _Float16 hi = (_Float16)v;
        int n_tile = r >> 4, colr = r & 15, ks = k >> 5, qd = (k >> 3) & 3, j = k & 7;
        int dst = W_BIG + m * 131072 + (n_tile * 4 + ks) * 1024 + (qd * 16 + colr) * 8 + j;
        ws[dst]       = hi;
        ws[dst + 512] = (_Float16)(v - (float)hi);
    } else if (idx < 344064) {
        int e = idx - 327680;              // [0, 16384)
        int r = e >> 5, k = e & 31;
        float v = (k < INW) ? Wih0[r * INW + k] : 0.0f;
        _Float16 hi = (_Float16)v;
        int n_tile = r >> 4, colr = r & 15, qd = k >> 3, j = k & 7;
        int dst = W_IH0 + n_tile * 1024 + (qd * 16 + colr) * 8 + j;
        ws[dst]       = hi;
        ws[dst + 512] = (_Float16)(v - (float)hi);
    } else if (idx < 348160) {
        int e = idx - 344064;              // [0, 4096)
        int r = e >> 7, k = e & 127;
        float v = (r < INW) ? Wl[(size_t)r * HID + k] : 0.0f;
        _Float16 hi = (_Float16)v;
        int n_tile = r >> 4, colr = r & 15, ks = k >> 5, qd = (k >> 3) & 3, j = k & 7;
        int dst = W_HEAD + (n_tile * 4 + ks) * 1024 + (qd * 16 + colr) * 8 + j;
        ws[dst]       = hi;
        ws[dst + 512] = (_Float16)(v - (float)hi);
    }
}

// ---------------- GEMM helpers (software-pipelined, sched_barrier-fenced) ----------------
// acc[j]: rows m = quad*4 + r, cols n = (j*4 + wv)*16 + col   (j = 0..7)
// Pure-f16 gemm (round 10/11: both lo corrections dropped, absmax bit-neutral).
// A from LDS h plane (row-major stride KP); B fragment tiles (coalesced lane*8).
// Pipeline: B tiles 6-slot (~250 cyc lookahead ~= L2 latency); A frags dbuf per ks.
__device__ __forceinline__ void gemm_h(f32x4 acc[8],
                                       const _Float16* __restrict__ A,
                                       const _Float16* __restrict__ B,
                                       int col, int q8, int wv, int lane)
{
    const _Float16* a_p = A + col * KP;
    const int l8 = lane * 8;
    const _Float16* Bw = B + (wv * 4) * 1024 + l8;   // tile (j,ks) at Bw + (j*16+ks)*1024

    f16x8 bh[6];
    f16x8 ah[2];

    // prologue: A frag for ks=0; B tiles for regions 0..5
    ah[0] = *(const f16x8*)(a_p + q8);
#pragma unroll
    for (int p = 0; p < 6; ++p) {
        const int pj = p & 7, pk = p >> 3;
        bh[p] = *(const f16x8*)(Bw + (pj * 16 + pk) * 1024);
    }
    __builtin_amdgcn_sched_barrier(0);

#pragma unroll
    for (int it = 0; it < 32; ++it) {
        const int ks = it >> 3, j = it & 7;
        const int sl = it % 6;      // B slot (6-deep)
        const int ka = ks & 1;      // A slot
        __builtin_amdgcn_s_setprio(1);
        acc[j] = __builtin_amdgcn_mfma_f32_16x16x32_f16(ah[ka], bh[sl], acc[j], 0, 0, 0);
        __builtin_amdgcn_s_setprio(0);
        // issue B load for region it+6 into the just-freed slot
        if (it < 26) {
            const int it6 = it + 6;
            bh[sl] = *(const f16x8*)(Bw + (((it6) & 7) * 16 + ((it6) >> 3)) * 1024);
        }
        // issue A frag load for ks+1 early in each ks (consumed 8 regions later)
        if (j == 0 && ks < 3)
            ah[ka ^ 1] = *(const f16x8*)(a_p + (ks + 1) * 32 + q8);
        __builtin_amdgcn_sched_barrier(0);   // pin the pipeline: nothing crosses
    }
}

// x-part for layer 0: K=32 (padded), 8 regions, 4-slot B pipeline (1/21 of work)
__device__ __forceinline__ void gemm_x(f32x4 acc[8],
                                       const _Float16* __restrict__ X,
                                       const _Float16* __restrict__ B,
                                       int col, int q8, int wv, int lane)
{
    const int l8 = lane * 8;
    const _Float16* Bw = B + wv * 1024 + l8;         // tile j at Bw + j*4*1024
    f16x8 ah = *(const f16x8*)(X + col * KP0 + q8);
    f16x8 bh[4];
#pragma unroll
    for (int p = 0; p < 4; ++p)
        bh[p] = *(const f16x8*)(Bw + p * 4 * 1024);
    __builtin_amdgcn_sched_barrier(0);
#pragma unroll
    for (int j = 0; j < 8; ++j) {
        const int sl = j & 3;
        __builtin_amdgcn_s_setprio(1);
        acc[j] = __builtin_amdgcn_mfma_f32_16x16x32_f16(ah, bh[sl], acc[j], 0, 0, 0);
        __builtin_amdgcn_s_setprio(0);
        if (j < 4)
            bh[sl] = *(const f16x8*)(Bw + (j + 4) * 4 * 1024);
        __builtin_amdgcn_sched_barrier(0);
    }
}

// gates + h write for one layer.
// Lane holds, for col groups cg=0,1 (c = cg*64 + wv*16 + col) and rows r=0..3:
//   zi = acc[0+cg][r], zf = acc[2+cg][r], zg = acc[4+cg][r], zo = acc[6+cg][r]
__device__ __forceinline__ void gates_store(f32x4 acc[8], f32x4 cst[2],
                                            _Float16* __restrict__ HsP,
                                            int quad, int col, int wv)
{
#pragma unroll
    for (int cg = 0; cg < 2; ++cg) {
        const int c = cg * 64 + wv * 16 + col;
#pragma unroll
        for (int r = 0; r < 4; ++r) {
            float zi = acc[0 + cg][r];
            float zf = acc[2 + cg][r];
            float zg = acc[4 + cg][r];
            float zo = acc[6 + cg][r];
            float ig = sigm(zi), fg = sigm(zf), og = sigm(zo), gg = tanh_(zg);
            float cn = fg * cst[cg][r] + ig * gg;
            cst[cg][r] = cn;
            float h = og * tanh_(cn);
            int m = quad * 4 + r;
            HsP[m * KP + c] = (_Float16)h;
        }
    }
}

// out[:, t, :] = h2 @ Wl^T + bl (waves 0..1 only: nt = wv)
__device__ __forceinline__ void head_out(const _Float16* __restrict__ wsp,
                                         const _Float16* __restrict__ Hs2,
                                         float* __restrict__ out, int b0, int t,
                                         int wv, int lane, int col, int quad, int q8,
                                         float blv)
{
    const int nt = wv;
    const _Float16* ah = Hs2 + col * KP;
    f32x4 o = (f32x4){0, 0, 0, 0};
#pragma unroll
    for (int ks = 0; ks < 4; ++ks) {
        const _Float16* bt = wsp + W_HEAD + (nt * 4 + ks) * 1024 + lane * 8;
        f16x8 a_h = *(const f16x8*)(ah + ks * 32 + q8);
        f16x8 b_h = *(const f16x8*)(bt);
        o = __builtin_amdgcn_mfma_f32_16x16x32_f16(a_h, b_h, o, 0, 0, 0);
    }
    int i = nt * 16 + col;
    if (i < INW) {
#pragma unroll
        for (int r = 0; r < 4; ++r) {
            int m = quad * 4 + r;
            out[(size_t)(b0 + m) * (TSTEPS * INW) + t * INW + i] = o[r] + blv;
        }
    }
}

// ---------------- main kernel ----------------
// 3-barrier schedule, 16-row blocks for 4 blocks/CU. NOTE launch bounds:
// empirically the VGPR budget = 256 / <2nd arg>; (256,2) -> cap 128, and
// actual VGPR ~115 <= 128 gives 16 waves/CU (4 blocks) at runtime.
//   rec-gemm Whh(l)*h_old(l)  [+ gemm_x / x-loads at l==0; Xs write at l==1; head(t-1) at l==2]
//   BARRIER   (anti-dep: all reads of Hs[l]-old done; visibility: h_new(l-1) published)
//   in-gemm Wih(l)*h_new(l-1)  [l>0]
//   gates(l) -> write Hs[l]
__global__ __launch_bounds__(THREADS, 2) void lstm_mfma(
    const float* __restrict__ x,
    const float* __restrict__ bih0, const float* __restrict__ bhh0,
    const float* __restrict__ bih1, const float* __restrict__ bhh1,
    const float* __restrict__ bih2, const float* __restrict__ bhh2,
    const float* __restrict__ bl,
    const _Float16* __restrict__ wsp,
    float* __restrict__ out)
{
    __shared__ _Float16 Hs[3][NROW][KP];      // [layer][m][k]  = 13056 B
    __shared__ _Float16 Xs[2][NROW][KP0];     // [buf][m][k]    = 2560 B
    __shared__ float    Bs[3][512];           // bih+bhh/layer  = 6144 B

    const int tid  = threadIdx.x;
    const int wv   = tid >> 6;
    const int lane = tid & 63;
    const int col  = lane & 15;
    const int quad = lane >> 4;
    const int q8   = quad * 8;
    const int b0   = blockIdx.x * NROW;

    // stage bias sums into LDS (saves persistent registers)
    for (int i = tid; i < 1536; i += THREADS) {
        int l = i >> 9, n = i & 511;
        const float* bi = (l == 0) ? bih0 : (l == 1) ? bih1 : bih2;
        const float* bh = (l == 0) ? bhh0 : (l == 1) ? bhh1 : bhh2;
        Bs[l][n] = bi[n] + bh[n];
    }
    // zero h state: 13056 B = 3264 floats
    for (int i = tid; i < 3264; i += THREADS) ((float*)Hs)[i] = 0.0f;

    // stage x[:, 0, :] as f16 into buffer 0 (K padded to 32)
    for (int ii = tid; ii < NROW * 32; ii += THREADS) {
        int m = ii >> 5, k = ii & 31;
        float v = (k < INW) ? x[(size_t)(b0 + m) * (TSTEPS * INW) + k] : 0.0f;
        Xs[0][m][k] = (_Float16)v;
    }

    f32x4 cst[3][2];
#pragma unroll
    for (int l = 0; l < 3; ++l) { cst[l][0] = (f32x4){0,0,0,0}; cst[l][1] = (f32x4){0,0,0,0}; }

    // weight pointers (fragment-ordered)
    const _Float16* Whh[3] = {wsp + W_BIG,  wsp + W_BIG + 131072, wsp + W_BIG + 262144};
    const _Float16* Wih[3] = {wsp + W_IH0, wsp + W_BIG + 393216, wsp + W_BIG + 524288};

    // head bias (waves 0..1 only)
    float blv = 0.0f;
    {
        int i = wv * 16 + col;
        if (wv < 2 && i < INW) blv = bl[i];
    }

    __syncthreads();

    int tb = 0;
#pragma unroll 1
    for (int t = 0; t < TSTEPS; ++t) {
        const int nb = tb ^ 1;
        const int t2 = t + 1;
        float xva[2];

#pragma unroll 1
        for (int l = 0; l < 3; ++l) {
            f32x4 acc[8];
#pragma unroll
            for (int j = 0; j < 8; ++j) {
                float bv = Bs[l][(j * 4 + wv) * 16 + col];
                acc[j] = (f32x4){bv, bv, bv, bv};
            }

            if (l == 0) {
                // issue x[t+1] loads early (latency hides under the L0 gemms)
                if (t2 < TSTEPS) {
#pragma unroll
                    for (int u = 0; u < 2; ++u) {
                        int ii = tid + u * THREADS;
                        int m = ii >> 5, k = ii & 31;
                        xva[u] = (k < INW) ? x[(size_t)(b0 + m) * (TSTEPS * INW) + t2 * INW + k] : 0.0f;
                    }
                }
                gemm_x(acc, &Xs[tb][0][0], Wih[0], col, q8, wv, lane);
            }

            // recurrent contribution (reads Hs[l] OLD)
            gemm_h(acc, &Hs[l][0][0], Whh[l], col, q8, wv, lane);

            if (l == 1 && t2 < TSTEPS) {
                // write x[t+1] to the LDS double-buffer (loads landed during L0/L1 gemms)
#pragma unroll
                for (int u = 0; u < 2; ++u) {
                    int ii = tid + u * THREADS;
                    int m = ii >> 5, k = ii & 31;
                    Xs[nb][m][k] = (_Float16)xva[u];
                }
            }
            if (l == 2 && t > 0 && wv < 2)
                head_out(wsp, &Hs[2][0][0], out, b0, t - 1,
                         wv, lane, col, quad, q8, blv);

            __syncthreads();   // reads of Hs[l]-old done (all waves); h_new(l-1) visible

            // input contribution (reads Hs[l-1] NEW)
            if (l > 0)
                gemm_h(acc, &Hs[l - 1][0][0], Wih[l], col, q8, wv, lane);

            gates_store(acc, cst[l], &Hs[l][0][0], quad, col, wv);
            // no barrier here: next iteration's rec gemm touches a different Hs buffer
        }

        tb = nb;
    }

    __syncthreads();   // h2(T-1) visible for the epilogue head
    if (wv < 2)
        head_out(wsp, &Hs[2][0][0], out, b0, TSTEPS - 1,
                 wv, lane, col, quad, q8, blv);
}

extern "C" void kernel_launch(void* const* d_in, const int* in_sizes, int n_in,
                              void* d_out, int out_size, void* d_ws, size_t ws_size,
                              hipStream_t stream) {
    const float* x    = (const float*)d_in[0];
    const float* Wih0 = (const float*)d_in[1];
    const float* Whh0 = (const float*)d_in[2];
    const float* bih0 = (const float*)d_in[3];
    const float* bhh0 = (const float*)d_in[4];
    const float* Wih1 = (const float*)d_in[5];
    const float* Whh1 = (const float*)d_in[6];
    const float* bih1 = (const float*)d_in[7];
    const float* bhh1 = (const float*)d_in[8];
    const float* Wih2 = (const float*)d_in[9];
    const float* Whh2 = (const float*)d_in[10];
    const float* bih2 = (const float*)d_in[11];
    const float* bhh2 = (const float*)d_in[12];
    const float* Wl   = (const float*)d_in[13];
    const float* bl   = (const float*)d_in[14];
    float* out = (float*)d_out;
    _Float16* ws = (_Float16*)d_ws;

    convert_w<<<(348160 + 255) / 256, 256, 0, stream>>>(Whh0, Whh1, Whh2, Wih1, Wih2, Wih0, Wl, ws);
    lstm_mfma<<<BATCH / NROW, THREADS, 0, stream>>>(
        x, bih0, bhh0, bih1, bhh1, bih2, bhh2, bl, ws, out);
}

// Round 15
// 474.777 us; speedup vs baseline: 2.1413x; 1.2448x over previous
//
#include <hip/hip_runtime.h>
#include <math.h>

#define BATCH  16384
#define TSTEPS 19
#define INW    17
#define HID    128
#define NROW   32          // batch rows per WG -> grid = 512 = 2 blocks/CU (B-reuse sweet spot)
#define THREADS 512        // 8 waves; wave wv owns j-tile wv (all 4 gates, both m-tiles)
#define KP     136         // padded row length (halfs) for h state (128+8)
#define KP0    40          // padded row length (halfs) for x (32+8)

typedef _Float16 f16x8 __attribute__((ext_vector_type(8)));
typedef float    f32x4 __attribute__((ext_vector_type(4)));

// ---- ws layout (halfs), MFMA-fragment-ordered tiles ----
#define W_BIG      0                 // 5 * 131072 = 655360
#define W_IH0      655360            // [512][32]: n_tile 0..31, tiles of 1024 (hi512|lo512)
#define W_HEAD     688128            // [32 rows][128]: (n_tile 0..1, ks 0..3) tiles of 1024
#define WS_HALFS   696320

__device__ __forceinline__ float fast_rcp(float x) { return __builtin_amdgcn_rcpf(x); }
__device__ __forceinline__ float sigm(float z)  { return fast_rcp(1.0f + __expf(-z)); }
__device__ __forceinline__ float tanh_(float z) { return 1.0f - 2.0f * fast_rcp(1.0f + __expf(2.0f * z)); }

// ---------------- weight conversion: fp32 -> f16 hi (lo planes written but unused) ----------------
__global__ void convert_w(const float* __restrict__ Whh0, const float* __restrict__ Whh1,
                          const float* __restrict__ Whh2, const float* __restrict__ Wih1,
                          const float* __restrict__ Wih2, const float* __restrict__ Wih0,
                          const float* __restrict__ Wl, _Float16* __restrict__ ws)
{
    int idx = blockIdx.x * 256 + threadIdx.x;
    if (idx < 327680) {
        int m = idx >> 16, e = idx & 65535;
        int r = e >> 7, k = e & 127;
        const float* src = (m == 0) ? Whh0 : (m == 1) ? Whh1 : (m == 2) ? Whh2
                          : (m == 3) ? Wih1 : Wih2;
        float v = src[e];
        _Float16 hi = (_Float16)v;
        int n_tile = r >> 4, colr = r & 15, ks = k >> 5, qd = (k >> 3) & 3, j = k & 7;
        int dst = W_BIG + m * 131072 + (n_tile * 4 + ks) * 1024 + (qd * 16 + colr) * 8 + j;
        ws[dst]       = hi;
        ws[dst + 512] = (_Float16)(v - (float)hi);
    } else if (idx < 344064) {
        int e = idx - 327680;              // [0, 16384)
        int r = e >> 5, k = e & 31;
        float v = (k < INW) ? Wih0[r * INW + k] : 0.0f;
        _Float16 hi = (_Float16)v;
        int n_tile = r >> 4, colr = r & 15, qd = k >> 3, j = k & 7;
        int dst = W_IH0 + n_tile * 1024 + (qd * 16 + colr) * 8 + j;
        ws[dst]       = hi;
        ws[dst + 512] = (_Float16)(v - (float)hi);
    } else if (idx < 348160) {
        int e = idx - 344064;              // [0, 4096)
        int r = e >> 7, k = e & 127;
        float v = (r < INW) ? Wl[(size_t)r * HID + k] : 0.0f;
        _Float16 hi = (_Float16)v;
        int n_tile = r >> 4, colr = r & 15, ks = k >> 5, qd = (k >> 3) & 3, j = k & 7;
        int dst = W_HEAD + (n_tile * 4 + ks) * 1024 + (qd * 16 + colr) * 8 + j;
        ws[dst]       = hi;
        ws[dst + 512] = (_Float16)(v - (float)hi);
    }
}

// ---------------- GEMM helpers (software-pipelined, sched_barrier-fenced) ----------------
// acc[mt][g]: rows m = mt*16 + quad*4 + r, cols n = g*128 + wv*16 + col
// Pure-f16 gemm: z = A_hi*B_hi (both lo corrections dropped; rounds 10/11 proved
// each drop bit-neutral on output absmax).
// A from LDS h plane (row-major stride KP); B fragment tiles (coalesced lane*8).
// Pipeline: B tiles 6-slot (issued 6 regions ahead > L2 latency); A frags dbuf per ks.
__device__ __forceinline__ void gemm_h(f32x4 acc[2][4],
                                       const _Float16* __restrict__ A,
                                       const _Float16* __restrict__ B,
                                       int col, int q8, int wv, int lane)
{
    const _Float16* a_p = A + col * KP;
    const int l8 = lane * 8;
    const _Float16* Bw = B + (wv * 4) * 1024 + l8;   // tile (ks,g) at Bw + (g*32+ks)*1024

    f16x8 bh[6];
    f16x8 ah0[2], ah1[2];

    // prologue: A frags for ks=0; B tiles for regions 0..5 (region r: g=r&3, ks=r>>2)
    ah0[0] = *(const f16x8*)(a_p + q8);
    ah1[0] = *(const f16x8*)(a_p + 16 * KP + q8);
#pragma unroll
    for (int p = 0; p < 6; ++p)
        bh[p] = *(const f16x8*)(Bw + ((p & 3) * 32 + (p >> 2)) * 1024);
    __builtin_amdgcn_sched_barrier(0);

#pragma unroll
    for (int it = 0; it < 16; ++it) {
        const int ks = it >> 2, g = it & 3;
        const int sl = it % 6;      // B slot (6-deep)
        const int ka = ks & 1;      // A slot
        __builtin_amdgcn_s_setprio(1);
        acc[0][g] = __builtin_amdgcn_mfma_f32_16x16x32_f16(ah0[ka], bh[sl], acc[0][g], 0, 0, 0);
        acc[1][g] = __builtin_amdgcn_mfma_f32_16x16x32_f16(ah1[ka], bh[sl], acc[1][g], 0, 0, 0);
        __builtin_amdgcn_s_setprio(0);
        // issue B load for region it+6 into the just-freed slot
        if (it < 10) {
            const int it6 = it + 6;
            bh[sl] = *(const f16x8*)(Bw + (((it6) & 3) * 32 + ((it6) >> 2)) * 1024);
        }
        // issue A frag loads for ks+1 early in each ks (consumed 4 regions later)
        if (g == 0 && ks < 3) {
            const int ko = (ks + 1) * 32 + q8;
            ah0[ka ^ 1] = *(const f16x8*)(a_p + ko);
            ah1[ka ^ 1] = *(const f16x8*)(a_p + 16 * KP + ko);
        }
        __builtin_amdgcn_sched_barrier(0);   // pin the pipeline: nothing crosses
    }
}

// x-part for layer 0: K=32 (padded), 4 regions, depth-2 B pipeline (1/21 of work)
__device__ __forceinline__ void gemm_x(f32x4 acc[2][4],
                                       const _Float16* __restrict__ X,
                                       const _Float16* __restrict__ B,
                                       int col, int q8, int wv, int lane)
{
    const int l8 = lane * 8;
    const _Float16* Bw = B + wv * 1024 + l8;         // tile g at Bw + g*8*1024
    f16x8 ah0 = *(const f16x8*)(X + col * KP0 + q8);
    f16x8 ah1 = *(const f16x8*)(X + (16 + col) * KP0 + q8);
    f16x8 bh[2];
    bh[0] = *(const f16x8*)(Bw);
    bh[1] = *(const f16x8*)(Bw + 8 * 1024);
    __builtin_amdgcn_sched_barrier(0);
#pragma unroll
    for (int g = 0; g < 4; ++g) {
        const int sl = g & 1;
        __builtin_amdgcn_s_setprio(1);
        acc[0][g] = __builtin_amdgcn_mfma_f32_16x16x32_f16(ah0, bh[sl], acc[0][g], 0, 0, 0);
        acc[1][g] = __builtin_amdgcn_mfma_f32_16x16x32_f16(ah1, bh[sl], acc[1][g], 0, 0, 0);
        __builtin_amdgcn_s_setprio(0);
        if (g < 2)
            bh[sl] = *(const f16x8*)(Bw + (g + 2) * 8 * 1024);
        __builtin_amdgcn_sched_barrier(0);
    }
}

// gates + h write for one layer (acc consumed, cst updated, h f16 -> LDS)
__device__ __forceinline__ void gates_store(f32x4 acc[2][4], f32x4 cst[2],
                                            _Float16* __restrict__ HsP,
                                            int quad, int col, int wv)
{
#pragma unroll
    for (int mt = 0; mt < 2; ++mt) {
#pragma unroll
        for (int r = 0; r < 4; ++r) {
            float zi = acc[mt][0][r];
            float zf = acc[mt][1][r];
            float zg = acc[mt][2][r];
            float zo = acc[mt][3][r];
            float ig = sigm(zi), fg = sigm(zf), og = sigm(zo), gg = tanh_(zg);
            float cn = fg * cst[mt][r] + ig * gg;
            cst[mt][r] = cn;
            float h = og * tanh_(cn);
            int m = mt * 16 + quad * 4 + r;
            int j = wv * 16 + col;
            HsP[m * KP + j] = (_Float16)h;
        }
    }
}

// out[:, t, :] = h2 @ Wl^T + bl (waves 0..3 only: mt = wv>>1, nt = wv&1)
__device__ __forceinline__ void head_out(const _Float16* __restrict__ wsp,
                                         const _Float16* __restrict__ Hs2,
                                         float* __restrict__ out, int b0, int t,
                                         int wv, int lane, int col, int quad, int q8,
                                         float blv)
{
    const int mt = wv >> 1, nt = wv & 1;
    const _Float16* ah = Hs2 + (mt * 16 + col) * KP;
    f32x4 o = (f32x4){0, 0, 0, 0};
#pragma unroll
    for (int ks = 0; ks < 4; ++ks) {
        const _Float16* bt = wsp + W_HEAD + (nt * 4 + ks) * 1024 + lane * 8;
        f16x8 a_h = *(const f16x8*)(ah + ks * 32 + q8);
        f16x8 b_h = *(const f16x8*)(bt);
        o = __builtin_amdgcn_mfma_f32_16x16x32_f16(a_h, b_h, o, 0, 0, 0);
    }
    int i = nt * 16 + col;
    if (i < INW) {
#pragma unroll
        for (int r = 0; r < 4; ++r) {
            int m = mt * 16 + quad * 4 + r;
            out[(size_t)(b0 + m) * (TSTEPS * INW) + t * INW + i] = o[r] + blv;
        }
    }
}

// ---------------- main kernel ----------------
// 3-barrier schedule (round 8). Per layer iteration:
//   rec-gemm Whh(l)*h_old(l)  [+ gemm_x / x-loads at l==0; Xs write at l==1; head(t-1) at l==2]
//   BARRIER   (anti-dep: all reads of Hs[l]-old done; visibility: h_new(l-1) published)
//   in-gemm Wih(l)*h_new(l-1)  [l>0]
//   gates(l) -> write Hs[l]
__global__ __launch_bounds__(THREADS, 2) void lstm_mfma(
    const float* __restrict__ x,
    const float* __restrict__ bih0, const float* __restrict__ bhh0,
    const float* __restrict__ bih1, const float* __restrict__ bhh1,
    const float* __restrict__ bih2, const float* __restrict__ bhh2,
    const float* __restrict__ bl,
    const _Float16* __restrict__ wsp,
    float* __restrict__ out)
{
    __shared__ _Float16 Hs[3][NROW][KP];      // [layer][m][k]  = 26112 B
    __shared__ _Float16 Xs[2][NROW][KP0];     // [buf][m][k]    = 5120 B
    __shared__ float    Bs[3][512];           // bih+bhh/layer  = 6144 B

    const int tid  = threadIdx.x;
    const int wv   = tid >> 6;
    const int lane = tid & 63;
    const int col  = lane & 15;
    const int quad = lane >> 4;
    const int q8   = quad * 8;
    const int b0   = blockIdx.x * NROW;

    // stage bias sums into LDS (saves persistent registers)
    for (int i = tid; i < 1536; i += THREADS) {
        int l = i >> 9, n = i & 511;
        const float* bi = (l == 0) ? bih0 : (l == 1) ? bih1 : bih2;
        const float* bh = (l == 0) ? bhh0 : (l == 1) ? bhh1 : bhh2;
        Bs[l][n] = bi[n] + bh[n];
    }
    // zero h state: 26112 B = 6528 floats
    for (int i = tid; i < 6528; i += THREADS) ((float*)Hs)[i] = 0.0f;

    // stage x[:, 0, :] as f16 into buffer 0 (K padded to 32)
    for (int ii = tid; ii < NROW * 32; ii += THREADS) {
        int m = ii >> 5, k = ii & 31;
        float v = (k < INW) ? x[(size_t)(b0 + m) * (TSTEPS * INW) + k] : 0.0f;
        Xs[0][m][k] = (_Float16)v;
    }

    f32x4 cst[3][2];
#pragma unroll
    for (int l = 0; l < 3; ++l) { cst[l][0] = (f32x4){0,0,0,0}; cst[l][1] = (f32x4){0,0,0,0}; }

    // weight pointers (fragment-ordered)
    const _Float16* Whh[3] = {wsp + W_BIG,  wsp + W_BIG + 131072, wsp + W_BIG + 262144};
    const _Float16* Wih[3] = {wsp + W_IH0, wsp + W_BIG + 393216, wsp + W_BIG + 524288};

    // head bias (waves 0..3 only)
    float blv = 0.0f;
    {
        int i = (wv & 1) * 16 + col;
        if (wv < 4 && i < INW) blv = bl[i];
    }

    __syncthreads();

    int tb = 0;
#pragma unroll 1
    for (int t = 0; t < TSTEPS; ++t) {
        const int nb = tb ^ 1;
        const int t2 = t + 1;
        float xva[2];

#pragma unroll 1
        for (int l = 0; l < 3; ++l) {
            f32x4 acc[2][4];
#pragma unroll
            for (int mt = 0; mt < 2; ++mt)
#pragma unroll
                for (int g = 0; g < 4; ++g) {
                    float bv = Bs[l][g * 128 + wv * 16 + col];
                    acc[mt][g] = (f32x4){bv, bv, bv, bv};
                }

            if (l == 0) {
                // issue x[t+1] loads early (latency hides under the L0 gemms)
                if (t2 < TSTEPS) {
#pragma unroll
                    for (int u = 0; u < 2; ++u) {
                        int ii = tid + u * THREADS;
                        int m = ii >> 5, k = ii & 31;
                        xva[u] = (k < INW) ? x[(size_t)(b0 + m) * (TSTEPS * INW) + t2 * INW + k] : 0.0f;
                    }
                }
                gemm_x(acc, &Xs[tb][0][0], Wih[0], col, q8, wv, lane);
            }

            // recurrent contribution (reads Hs[l] OLD)
            gemm_h(acc, &Hs[l][0][0], Whh[l], col, q8, wv, lane);

            if (l == 1 && t2 < TSTEPS) {
                // write x[t+1] to the LDS double-buffer (loads landed during L0/L1 gemms)
#pragma unroll
                for (int u = 0; u < 2; ++u) {
                    int ii = tid + u * THREADS;
                    int m = ii >> 5, k = ii & 31;
                    Xs[nb][m][k] = (_Float16)xva[u];
                }
            }
            if (l == 2 && t > 0 && wv < 4)
                head_out(wsp, &Hs[2][0][0], out, b0, t - 1,
                         wv, lane, col, quad, q8, blv);

            __syncthreads();   // reads of Hs[l]-old done (all waves); h_new(l-1) visible

            // input contribution (reads Hs[l-1] NEW)
            if (l > 0)
                gemm_h(acc, &Hs[l - 1][0][0], Wih[l], col, q8, wv, lane);

            gates_store(acc, cst[l], &Hs[l][0][0], quad, col, wv);
            // no barrier here: next iteration's rec gemm touches a different Hs buffer
        }

        tb = nb;
    }

    __syncthreads();   // h2(T-1) visible for the epilogue head
    if (wv < 4)
        head_out(wsp, &Hs[2][0][0], out, b0, TSTEPS - 1,
                 wv, lane, col, quad, q8, blv);
}

extern "C" void kernel_launch(void* const* d_in, const int* in_sizes, int n_in,
                              void* d_out, int out_size, void* d_ws, size_t ws_size,
                              hipStream_t stream) {
    const float* x    = (const float*)d_in[0];
    const float* Wih0 = (const float*)d_in[1];
    const float* Whh0 = (const float*)d_in[2];
    const float* bih0 = (const float*)d_in[3];
    const float* bhh0 = (const float*)d_in[4];
    const float* Wih1 = (const float*)d_in[5];
    const float* Whh1 = (const float*)d_in[6];
    const float* bih1 = (const float*)d_in[7];
    const float* bhh1 = (const float*)d_in[8];
    const float* Wih2 = (const float*)d_in[9];
    const float* Whh2 = (const float*)d_in[10];
    const float* bih2 = (const float*)d_in[11];
    const float* bhh2 = (const float*)d_in[12];
    const float* Wl   = (const float*)d_in[13];
    const float* bl   = (const float*)d_in[14];
    float* out = (float*)d_out;
    _Float16* ws = (_Float16*)d_ws;

    convert_w<<<(348160 + 255) / 256, 256, 0, stream>>>(Whh0, Whh1, Whh2, Wih1, Wih2, Wih0, Wl, ws);
    lstm_mfma<<<BATCH / NROW, THREADS, 0, stream>>>(
        x, bih0, bhh0, bih1, bhh1, bih2, bhh2, bl, ws, out);
}